// Round 1
// baseline (491.842 us; speedup 1.0000x reference)
//
#include <hip/hip_runtime.h>

#define NN 8192
#define DD 128
#define DEG 32
#define EE (NN*DEG)
#define AA 64
#define KMSG 257  // 2D+1

// ---- ws layout (bytes) ----
// counts:   0        (NN*4      = 32768)
// inv:      32768    (EE*4      = 1048576)
// agg:      1081344  (NN*DD*4   = 4194304)
// node_sum: 5275648  (DD*4      = 512)
// Wt_msg:   5276160  (KMSG*DD*4 = 131584)   k-major [257][128]
// wt_ih:    5407744  (384*DD*4  = 196608)   k-major [128][384]
// wt_hh:    5604352  (384*DD*4  = 196608)
// total:    5800960  (~5.8 MB)

__global__ void prep_kernel(const float* __restrict__ W_msg,
                            const float* __restrict__ w_ih,
                            const float* __restrict__ w_hh,
                            int* __restrict__ counts, float* __restrict__ node_sum,
                            float* __restrict__ Wt_msg, float* __restrict__ wt_ih,
                            float* __restrict__ wt_hh)
{
    int idx = blockIdx.x * blockDim.x + threadIdx.x;
    if (idx < NN) counts[idx] = 0;
    if (idx < DD) node_sum[idx] = 0.f;
    if (idx < KMSG * DD) {
        int k = idx / DD, f = idx % DD;
        Wt_msg[idx] = W_msg[f * KMSG + k];
    }
    if (idx < 384 * DD) {
        int k = idx / 384, g = idx % 384;
        wt_ih[idx] = w_ih[g * DD + k];
        wt_hh[idx] = w_hh[g * DD + k];
    }
}

__global__ void build_inv_kernel(const int* __restrict__ dst_idx,
                                 int* __restrict__ counts, int* __restrict__ inv)
{
    int e = blockIdx.x * blockDim.x + threadIdx.x;
    if (e < EE) {
        int d = dst_idx[e];
        int slot = atomicAdd(&counts[d], 1);
        if (slot < DEG) inv[d * DEG + slot] = e;
    }
}

// one workgroup (256 threads) per dst node
__global__ __launch_bounds__(256) void msg_agg_kernel(
    const float* __restrict__ nf, const float* __restrict__ efeat,
    const int* __restrict__ src_idx, const int* __restrict__ counts,
    const int* __restrict__ inv, const float* __restrict__ Wt_msg,
    const float* __restrict__ b_msg, float* __restrict__ agg)
{
    const int d = blockIdx.x;
    const int t = threadIdx.x;
    __shared__ __align__(16) float comb[DEG][260];  // padded row stride: 1040B, 16B-aligned
    __shared__ int   s_src[DEG];
    __shared__ float s_ef[DEG];
    __shared__ float partial[2][DD];

    const int nv = min(counts[d], DEG);
    if (t < DEG) {
        int s = -1; float ev = 0.f;
        if (t < nv) {
            int e = inv[d * DEG + t];
            s = src_idx[e];
            ev = efeat[(size_t)s * NN + d];
        }
        s_src[t] = s; s_ef[t] = ev;
    }
    __syncthreads();

    // stage combined rows [src(128) | dst(128) | ef(1)]
    for (int j = 0; j < DEG; ++j) {
        int s = s_src[j];
        float v = 0.f;
        if (s >= 0)
            v = (t < DD) ? nf[(size_t)s * DD + t] : nf[(size_t)d * DD + (t - DD)];
        comb[j][t] = v;
        if (t == 0) comb[j][256] = s_ef[j];
        if (t < 3)  comb[j][257 + t] = 0.f;
    }
    __syncthreads();

    const int f = t & (DD - 1);
    const int h = t >> 7;           // which half of the 32 edges
    float acc[16];
#pragma unroll
    for (int i = 0; i < 16; ++i) acc[i] = 0.f;

    for (int kk = 0; kk < 256; kk += 8) {
        float w[8];
#pragma unroll
        for (int u = 0; u < 8; ++u) w[u] = Wt_msg[(kk + u) * DD + f];  // coalesced
#pragma unroll
        for (int i = 0; i < 16; ++i) {
            const int j = h * 16 + i;
            const float4 c0 = *(const float4*)&comb[j][kk];
            const float4 c1 = *(const float4*)&comb[j][kk + 4];
            acc[i] += w[0]*c0.x + w[1]*c0.y + w[2]*c0.z + w[3]*c0.w
                    + w[4]*c1.x + w[5]*c1.y + w[6]*c1.z + w[7]*c1.w;
        }
    }
    {
        const float w256 = Wt_msg[256 * DD + f];
#pragma unroll
        for (int i = 0; i < 16; ++i) acc[i] += w256 * comb[h * 16 + i][256];
    }

    const float bm = b_msg[f];
    float sum = 0.f;
#pragma unroll
    for (int i = 0; i < 16; ++i) {
        const int j = h * 16 + i;
        const float m = fmaxf(acc[i] + bm, 0.f);
        sum += (j < nv) ? m : 0.f;
    }
    partial[h][f] = sum;
    __syncthreads();
    if (t < DD) agg[(size_t)d * DD + t] = partial[0][t] + partial[1][t];
}

// 32 nodes per block; computes GRU update and accumulates node_sum
__global__ __launch_bounds__(256) void gru_kernel(
    const float* __restrict__ nf, const float* __restrict__ agg,
    const float* __restrict__ wt_ih, const float* __restrict__ wt_hh,
    const float* __restrict__ b_ih, const float* __restrict__ b_hh,
    float* __restrict__ node_sum)
{
    const int n0 = blockIdx.x * 32;
    const int t = threadIdx.x;
    __shared__ __align__(16) float aggT[32][DD];
    __shared__ __align__(16) float nfT[32][DD];
    for (int idx = t; idx < 32 * DD; idx += 256) {
        int j = idx >> 7, k = idx & 127;
        aggT[j][k] = agg[(size_t)(n0 + j) * DD + k];
        nfT[j][k]  = nf[(size_t)(n0 + j) * DD + k];
    }
    __syncthreads();

    const int f  = t & 127;
    const int jg = t >> 7;
    const float bir = b_ih[f], biz = b_ih[128 + f], bin = b_ih[256 + f];
    const float bhr = b_hh[f], bhz = b_hh[128 + f], bhn = b_hh[256 + f];
    float uloc = 0.f;

    for (int p = 0; p < 4; ++p) {
        const int jb = p * 8 + jg * 4;
        float ir[4] = {0,0,0,0}, iz[4] = {0,0,0,0}, in_[4] = {0,0,0,0};
        float hr[4] = {0,0,0,0}, hz[4] = {0,0,0,0}, hn[4] = {0,0,0,0};
        for (int k = 0; k < DD; ++k) {
            const float wir = wt_ih[k * 384 + f];
            const float wiz = wt_ih[k * 384 + 128 + f];
            const float win = wt_ih[k * 384 + 256 + f];
            const float whr = wt_hh[k * 384 + f];
            const float whz = wt_hh[k * 384 + 128 + f];
            const float whn = wt_hh[k * 384 + 256 + f];
#pragma unroll
            for (int i = 0; i < 4; ++i) {
                const float a  = aggT[jb + i][k];
                const float hv = nfT[jb + i][k];
                ir[i] += wir * a;  iz[i] += wiz * a;  in_[i] += win * a;
                hr[i] += whr * hv; hz[i] += whz * hv; hn[i] += whn * hv;
            }
        }
#pragma unroll
        for (int i = 0; i < 4; ++i) {
            const float r = 1.f / (1.f + expf(-(ir[i] + bir + hr[i] + bhr)));
            const float z = 1.f / (1.f + expf(-(iz[i] + biz + hz[i] + bhz)));
            const float n = tanhf(in_[i] + bin + r * (hn[i] + bhn));
            const float h = nfT[jb + i][f];
            uloc += (1.f - z) * n + z * h;
        }
    }
    atomicAdd(&node_sum[f], uloc);
}

__global__ void policy_kernel(const float* __restrict__ node_sum,
                              const float* __restrict__ W_pol,
                              const float* __restrict__ b_pol,
                              float* __restrict__ out)
{
    int a = threadIdx.x;
    if (a < AA) {
        float s = b_pol[a];
        for (int k = 0; k < DD; ++k) s += node_sum[k] * W_pol[a * DD + k];
        out[a] = s;
    }
}

extern "C" void kernel_launch(void* const* d_in, const int* in_sizes, int n_in,
                              void* d_out, int out_size, void* d_ws, size_t ws_size,
                              hipStream_t stream)
{
    const float* nf    = (const float*)d_in[0];
    const float* efeat = (const float*)d_in[1];
    const int*   src   = (const int*)d_in[2];
    const int*   dst   = (const int*)d_in[3];
    const float* W_msg = (const float*)d_in[4];
    const float* b_msg = (const float*)d_in[5];
    const float* w_ih  = (const float*)d_in[6];
    const float* w_hh  = (const float*)d_in[7];
    const float* b_ih  = (const float*)d_in[8];
    const float* b_hh  = (const float*)d_in[9];
    const float* W_pol = (const float*)d_in[10];
    const float* b_pol = (const float*)d_in[11];
    float* out = (float*)d_out;

    char* ws = (char*)d_ws;
    int*   counts   = (int*)(ws + 0);
    int*   inv      = (int*)(ws + 32768);
    float* agg      = (float*)(ws + 1081344);
    float* node_sum = (float*)(ws + 5275648);
    float* Wt_msg   = (float*)(ws + 5276160);
    float* wt_ih    = (float*)(ws + 5407744);
    float* wt_hh    = (float*)(ws + 5604352);

    prep_kernel<<<192, 256, 0, stream>>>(W_msg, w_ih, w_hh, counts, node_sum,
                                         Wt_msg, wt_ih, wt_hh);
    build_inv_kernel<<<EE / 256, 256, 0, stream>>>(dst, counts, inv);
    msg_agg_kernel<<<NN, 256, 0, stream>>>(nf, efeat, src, counts, inv,
                                           Wt_msg, b_msg, agg);
    gru_kernel<<<NN / 32, 256, 0, stream>>>(nf, agg, wt_ih, wt_hh, b_ih, b_hh,
                                            node_sum);
    policy_kernel<<<1, 64, 0, stream>>>(node_sum, W_pol, b_pol, out);
}

// Round 2
// 98.673 us; speedup vs baseline: 4.9845x; 4.9845x over previous
//
#include <hip/hip_runtime.h>

#define NN 8192
#define DD 128
#define DEG 32
#define EE (NN*DEG)
#define AA 64
#define KP 136   // padded K stride in bf16 elements (272 B)

using short8 = __attribute__((ext_vector_type(8))) short;
using f32x4  = __attribute__((ext_vector_type(4))) float;

__device__ __forceinline__ unsigned short f2bf(float x) {
    unsigned u = __builtin_bit_cast(unsigned, x);
    u += 0x7FFFu + ((u >> 16) & 1u);
    return (unsigned short)(u >> 16);
}

// ---- ws layout (bytes) ----
// counts   0        32768
// inv      32768    1048576
// agg      1081344  4194304
// dstpart  5275648  4194304
// node_sum 9469952  512
// w3f      9470464  512
// W1bf     9470976  34816   (bf16 [128][136] = W_msg[:, 0:128])
// W2bf     9505792  34816   (bf16 [128][136] = W_msg[:, 128:256])
// wibf     9540608  104448  (bf16 [384][136])
// whbf     9645056  104448
// end      9749504  (~9.75 MB)

__global__ void prep_kernel(const float* __restrict__ W_msg,
                            const float* __restrict__ w_ih,
                            const float* __restrict__ w_hh,
                            int* __restrict__ counts, float* __restrict__ node_sum,
                            float* __restrict__ w3f,
                            unsigned short* __restrict__ W1bf,
                            unsigned short* __restrict__ W2bf,
                            unsigned short* __restrict__ wibf,
                            unsigned short* __restrict__ whbf)
{
    int idx = blockIdx.x * 256 + threadIdx.x;
    if (idx < NN) counts[idx] = 0;
    if (idx < DD) { node_sum[idx] = 0.f; w3f[idx] = W_msg[idx * 257 + 256]; }
    if (idx < DD * KP) {
        int f = idx / KP, k = idx % KP;
        W1bf[idx] = f2bf((k < DD) ? W_msg[f * 257 + k] : 0.f);
        W2bf[idx] = f2bf((k < DD) ? W_msg[f * 257 + 128 + k] : 0.f);
    }
    if (idx < 384 * KP) {
        int g = idx / KP, k = idx % KP;
        wibf[idx] = f2bf((k < DD) ? w_ih[g * DD + k] : 0.f);
        whbf[idx] = f2bf((k < DD) ? w_hh[g * DD + k] : 0.f);
    }
}

__global__ void build_inv_kernel(const int* __restrict__ dst_idx,
                                 int* __restrict__ counts, int* __restrict__ inv)
{
    int e = blockIdx.x * blockDim.x + threadIdx.x;
    if (e < EE) {
        int d = dst_idx[e];
        int slot = atomicAdd(&counts[d], 1);
        if (slot < DEG) inv[d * DEG + slot] = e;
    }
}

// dstpart[i][f] = sum_k nf[i][k] * W_msg[f][128+k]; 64 blocks x 128 rows
__global__ __launch_bounds__(256) void dst_gemm_kernel(
    const float* __restrict__ nf, const unsigned short* __restrict__ W2bf,
    float* __restrict__ dstpart)
{
    __shared__ __align__(16) unsigned short Asz[128 * KP];
    __shared__ __align__(16) unsigned short Bsz[128 * KP];
    const int t = threadIdx.x;
    const int blk = blockIdx.x;

    {   // B copy (34816 B = 2176 uint4)
        const uint4* g = (const uint4*)W2bf;
        uint4* l = (uint4*)Bsz;
        for (int i = t; i < 2176; i += 256) l[i] = g[i];
    }
    for (int rr = 0; rr < 16; ++rr) {  // A: 128 rows of nf, f32 -> bf16
        int i = rr * 8 + (t >> 5);
        int c4 = (t & 31) * 4;
        const float4 v = *(const float4*)&nf[(size_t)(blk * 128 + i) * DD + c4];
        unsigned short h[4] = { f2bf(v.x), f2bf(v.y), f2bf(v.z), f2bf(v.w) };
        *(uint2*)&Asz[i * KP + c4] = *(uint2*)h;
    }
    __syncthreads();

    const int w = t >> 6, l = t & 63, p = l & 15, q = l >> 4;
    f32x4 acc[2][8];
    const f32x4 z4 = {0.f, 0.f, 0.f, 0.f};
#pragma unroll
    for (int m = 0; m < 2; ++m)
#pragma unroll
        for (int n = 0; n < 8; ++n) acc[m][n] = z4;

#pragma unroll
    for (int ks = 0; ks < 4; ++ks) {
        short8 a0 = *(const short8*)&Asz[(w * 32 + p) * KP + ks * 32 + q * 8];
        short8 a1 = *(const short8*)&Asz[(w * 32 + 16 + p) * KP + ks * 32 + q * 8];
#pragma unroll
        for (int n = 0; n < 8; ++n) {
            short8 b = *(const short8*)&Bsz[(n * 16 + p) * KP + ks * 32 + q * 8];
            acc[0][n] = __builtin_amdgcn_mfma_f32_16x16x32_bf16(a0, b, acc[0][n], 0, 0, 0);
            acc[1][n] = __builtin_amdgcn_mfma_f32_16x16x32_bf16(a1, b, acc[1][n], 0, 0, 0);
        }
    }
#pragma unroll
    for (int n = 0; n < 8; ++n)
#pragma unroll
        for (int m = 0; m < 2; ++m)
#pragma unroll
            for (int r = 0; r < 4; ++r)
                dstpart[(size_t)(blk * 128 + w * 32 + m * 16 + q * 4 + r) * DD + n * 16 + p] = acc[m][n][r];
}

// one block = 4 dst nodes (128 edge rows); MFMA src-GEMM + fused relu/agg
__global__ __launch_bounds__(256) void msg_agg_kernel(
    const float* __restrict__ nf, const float* __restrict__ efeat,
    const int* __restrict__ src_idx, const int* __restrict__ counts,
    const int* __restrict__ inv, const unsigned short* __restrict__ W1bf,
    const float* __restrict__ b_msg, const float* __restrict__ w3f,
    const float* __restrict__ dstpart, float* __restrict__ agg)
{
    __shared__ __align__(16) unsigned short Asz[128 * KP];
    __shared__ __align__(16) unsigned short Bsz[128 * KP];
    __shared__ int   s_src[128];
    __shared__ float s_ef[128];
    __shared__ int   s_nv[4];

    const int t = threadIdx.x;
    const int blk = blockIdx.x;

    {   // B copy
        const uint4* g = (const uint4*)W1bf;
        uint4* l = (uint4*)Bsz;
        for (int i = t; i < 2176; i += 256) l[i] = g[i];
    }
    if (t < 128) {
        int d = blk * 4 + (t >> 5);
        int e = inv[d * DEG + (t & 31)];
        int s = src_idx[e];
        s_src[t] = s;
        s_ef[t] = efeat[(size_t)s * NN + d];
    }
    if (t < 4) s_nv[t] = min(counts[blk * 4 + t], DEG);
    __syncthreads();

    for (int rr = 0; rr < 16; ++rr) {  // gather A rows, f32 -> bf16
        int i = rr * 8 + (t >> 5);
        int c4 = (t & 31) * 4;
        const float4 v = *(const float4*)&nf[(size_t)s_src[i] * DD + c4];
        unsigned short h[4] = { f2bf(v.x), f2bf(v.y), f2bf(v.z), f2bf(v.w) };
        *(uint2*)&Asz[i * KP + c4] = *(uint2*)h;
    }
    __syncthreads();

    const int w = t >> 6, l = t & 63, p = l & 15, q = l >> 4;
    f32x4 acc[2][8];
    const f32x4 z4 = {0.f, 0.f, 0.f, 0.f};
#pragma unroll
    for (int m = 0; m < 2; ++m)
#pragma unroll
        for (int n = 0; n < 8; ++n) acc[m][n] = z4;

#pragma unroll
    for (int ks = 0; ks < 4; ++ks) {
        short8 a0 = *(const short8*)&Asz[(w * 32 + p) * KP + ks * 32 + q * 8];
        short8 a1 = *(const short8*)&Asz[(w * 32 + 16 + p) * KP + ks * 32 + q * 8];
#pragma unroll
        for (int n = 0; n < 8; ++n) {
            short8 b = *(const short8*)&Bsz[(n * 16 + p) * KP + ks * 32 + q * 8];
            acc[0][n] = __builtin_amdgcn_mfma_f32_16x16x32_bf16(a0, b, acc[0][n], 0, 0, 0);
            acc[1][n] = __builtin_amdgcn_mfma_f32_16x16x32_bf16(a1, b, acc[1][n], 0, 0, 0);
        }
    }

    // epilogue: per wave -> node d, rows j = m*16 + q*4 + r
    const int d = blk * 4 + w;
    const int nv = s_nv[w];
#pragma unroll
    for (int nt = 0; nt < 8; ++nt) {
        const int col = nt * 16 + p;
        const float dp = dstpart[(size_t)d * DD + col];
        const float bv = b_msg[col];
        const float w3 = w3f[col];
        float sum = 0.f;
#pragma unroll
        for (int m = 0; m < 2; ++m)
#pragma unroll
            for (int r = 0; r < 4; ++r) {
                const int j = m * 16 + q * 4 + r;
                float val = acc[m][nt][r] + dp + s_ef[w * 32 + j] * w3 + bv;
                val = fmaxf(val, 0.f);
                sum += (j < nv) ? val : 0.f;
            }
        sum += __shfl_xor(sum, 16);
        sum += __shfl_xor(sum, 32);
        if (q == 0) agg[(size_t)d * DD + col] = sum;
    }
}

// 32 nodes/block, 6 waves: wave g computes one gate matrix [32x128] via MFMA,
// gates exchanged through LDS, elementwise GRU + node_sum reduction fused.
__global__ __launch_bounds__(384) void gru_kernel(
    const float* __restrict__ nf, const float* __restrict__ agg,
    const unsigned short* __restrict__ wibf, const unsigned short* __restrict__ whbf,
    const float* __restrict__ b_ih, const float* __restrict__ b_hh,
    float* __restrict__ node_sum)
{
    __shared__ __align__(16) unsigned short Aag[32 * KP];
    __shared__ __align__(16) unsigned short Anf[32 * KP];
    __shared__ float gate_s[6][32][132];

    const int t = threadIdx.x;
    const int n0 = blockIdx.x * 32;

    for (int i = t; i < 1024; i += 384) {   // 32 rows x 32 float4
        int row = i >> 5, c4 = (i & 31) * 4;
        float4 va = *(const float4*)&agg[(size_t)(n0 + row) * DD + c4];
        float4 vn = *(const float4*)&nf[(size_t)(n0 + row) * DD + c4];
        unsigned short ha[4] = { f2bf(va.x), f2bf(va.y), f2bf(va.z), f2bf(va.w) };
        unsigned short hb[4] = { f2bf(vn.x), f2bf(vn.y), f2bf(vn.z), f2bf(vn.w) };
        *(uint2*)&Aag[row * KP + c4] = *(uint2*)ha;
        *(uint2*)&Anf[row * KP + c4] = *(uint2*)hb;
    }
    __syncthreads();

    const int wv = t >> 6;          // gate 0..5: ir,iz,in,hr,hz,hn
    const int l = t & 63, p = l & 15, q = l >> 4;
    const unsigned short* wb = (wv < 3) ? wibf : whbf;
    const int rowbase = (wv % 3) * 128;
    const unsigned short* As = (wv < 3) ? Aag : Anf;

    f32x4 acc[2][8];
    const f32x4 z4 = {0.f, 0.f, 0.f, 0.f};
#pragma unroll
    for (int m = 0; m < 2; ++m)
#pragma unroll
        for (int n = 0; n < 8; ++n) acc[m][n] = z4;

#pragma unroll
    for (int ks = 0; ks < 4; ++ks) {
        short8 a0 = *(const short8*)&As[(p) * KP + ks * 32 + q * 8];
        short8 a1 = *(const short8*)&As[(16 + p) * KP + ks * 32 + q * 8];
#pragma unroll
        for (int n = 0; n < 8; ++n) {
            short8 b = *(const short8*)&wb[(size_t)(rowbase + n * 16 + p) * KP + ks * 32 + q * 8];
            acc[0][n] = __builtin_amdgcn_mfma_f32_16x16x32_bf16(a0, b, acc[0][n], 0, 0, 0);
            acc[1][n] = __builtin_amdgcn_mfma_f32_16x16x32_bf16(a1, b, acc[1][n], 0, 0, 0);
        }
    }
#pragma unroll
    for (int n = 0; n < 8; ++n)
#pragma unroll
        for (int m = 0; m < 2; ++m)
#pragma unroll
            for (int r = 0; r < 4; ++r)
                gate_s[wv][m * 16 + q * 4 + r][n * 16 + p] = acc[m][n][r];
    __syncthreads();

    const int f = t & 127;
    const int g3 = t >> 7;          // 0..2
    const float bir = b_ih[f], biz = b_ih[128 + f], bin = b_ih[256 + f];
    const float bhr = b_hh[f], bhz = b_hh[128 + f], bhn = b_hh[256 + f];
    float uloc = 0.f;
    for (int j = g3; j < 32; j += 3) {
        const float ir = gate_s[0][j][f], iz = gate_s[1][j][f], inn = gate_s[2][j][f];
        const float hr = gate_s[3][j][f], hz = gate_s[4][j][f], hn = gate_s[5][j][f];
        const float h = nf[(size_t)(n0 + j) * DD + f];
        const float r = 1.f / (1.f + expf(-(ir + bir + hr + bhr)));
        const float z = 1.f / (1.f + expf(-(iz + biz + hz + bhz)));
        const float n = tanhf(inn + bin + r * (hn + bhn));
        uloc += (1.f - z) * n + z * h;
    }
    atomicAdd(&node_sum[f], uloc);
}

__global__ void policy_kernel(const float* __restrict__ node_sum,
                              const float* __restrict__ W_pol,
                              const float* __restrict__ b_pol,
                              float* __restrict__ out)
{
    int a = threadIdx.x;
    if (a < AA) {
        float s = b_pol[a];
        for (int k = 0; k < DD; ++k) s += node_sum[k] * W_pol[a * DD + k];
        out[a] = s;
    }
}

extern "C" void kernel_launch(void* const* d_in, const int* in_sizes, int n_in,
                              void* d_out, int out_size, void* d_ws, size_t ws_size,
                              hipStream_t stream)
{
    const float* nf    = (const float*)d_in[0];
    const float* efeat = (const float*)d_in[1];
    const int*   src   = (const int*)d_in[2];
    const int*   dst   = (const int*)d_in[3];
    const float* W_msg = (const float*)d_in[4];
    const float* b_msg = (const float*)d_in[5];
    const float* w_ih  = (const float*)d_in[6];
    const float* w_hh  = (const float*)d_in[7];
    const float* b_ih  = (const float*)d_in[8];
    const float* b_hh  = (const float*)d_in[9];
    const float* W_pol = (const float*)d_in[10];
    const float* b_pol = (const float*)d_in[11];
    float* out = (float*)d_out;

    char* ws = (char*)d_ws;
    int*            counts   = (int*)(ws + 0);
    int*            inv      = (int*)(ws + 32768);
    float*          agg      = (float*)(ws + 1081344);
    float*          dstpart  = (float*)(ws + 5275648);
    float*          node_sum = (float*)(ws + 9469952);
    float*          w3f      = (float*)(ws + 9470464);
    unsigned short* W1bf     = (unsigned short*)(ws + 9470976);
    unsigned short* W2bf     = (unsigned short*)(ws + 9505792);
    unsigned short* wibf     = (unsigned short*)(ws + 9540608);
    unsigned short* whbf     = (unsigned short*)(ws + 9645056);

    prep_kernel<<<256, 256, 0, stream>>>(W_msg, w_ih, w_hh, counts, node_sum,
                                         w3f, W1bf, W2bf, wibf, whbf);
    build_inv_kernel<<<EE / 256, 256, 0, stream>>>(dst, counts, inv);
    dst_gemm_kernel<<<64, 256, 0, stream>>>(nf, W2bf, dstpart);
    msg_agg_kernel<<<2048, 256, 0, stream>>>(nf, efeat, src, counts, inv,
                                             W1bf, b_msg, w3f, dstpart, agg);
    gru_kernel<<<256, 384, 0, stream>>>(nf, agg, wibf, whbf, b_ih, b_hh, node_sum);
    policy_kernel<<<1, 64, 0, stream>>>(node_sum, W_pol, b_pol, out);
}